// Round 4
// baseline (232.066 us; speedup 1.0000x reference)
//
#include <hip/hip_runtime.h>

#define C_IN   128
#define H_IN   56
#define W_IN   56
#define HW     3136      // 56*56
#define CHW    401408    // 128*3136
#define O_OUT  256
#define OHW    802816    // 256*3136

#define LDK 72           // fallback padded layout

typedef __bf16 bf16x8 __attribute__((ext_vector_type(8)));
typedef float  f32x4  __attribute__((ext_vector_type(4)));
typedef unsigned short ushort_t;
typedef ushort_t ushort8 __attribute__((ext_vector_type(8)));

__device__ __forceinline__ ushort_t f2bf(float f) {
    union { float f; unsigned u; } v; v.f = f;
    unsigned r = (v.u + 0x7fffu + ((v.u >> 16) & 1u)) >> 16;
    return (ushort_t)r;
}

// ============================ FAST PATH ============================
// Weights: w[o][c][kh][kw] fp32 -> wbf[s][o][c&63] bf16, s = (kh*3+kw)*2 + (c>>6).
__global__ void wt3_kernel(const float* __restrict__ w, ushort_t* __restrict__ wbf) {
    int idx = blockIdx.x * 256 + threadIdx.x;        // 9*256*128 = 294912
    if (idx >= 9 * 256 * 128) return;
    int pos = idx >> 15;
    int rem = idx & 32767;
    int o   = rem >> 7;
    int c   = rem & 127;
    int s   = pos * 2 + (c >> 6);
    wbf[((s * 256 + o) << 6) + (c & 63)] = f2bf(w[o * 1152 + c * 9 + pos]);
}

// conv7 = conv6 + explicit register-pipelined main loop:
//  - afb[2][4]: next-next iteration's weight frags (global/L2), issued right
//    after the burst that frees the buffer -> one full MFMA burst in flight
//  - bvb[2][7]: next iteration's patch frags (LDS), issued before the burst
//  - all waits become compiler-emitted COUNTED vmcnt/lgkmcnt (never drains)
__global__ __launch_bounds__(256, 2)
void conv7_kernel(const float* __restrict__ x, const ushort_t* __restrict__ wbf,
                  const float* __restrict__ bias, float* __restrict__ out) {
    __shared__ ushort_t patch[232 * 128];   // 59,392 B (4 rows x 58 cols x 128 ch)

    const int tid  = threadIdx.x;
    const int lane = tid & 63;
    const int wave = tid >> 6;      // 0..3 -> o-slice
    const int l15  = lane & 15;
    const int quad = lane >> 4;
    const int om   = wave * 64;

    // block -> (n, h0), XCD-aware bijective swizzle (896 = 8 * 112)
    int b = blockIdx.x;
    b = (b & 7) * 112 + (b >> 3);
    const int n  = b / 28;
    const int h0 = (b - n * 28) * 2;

    // ---- integrated staging: x fp32 NCHW -> patch bf16 [pp][slot^] ----
    if (tid < 232) {
        const int pr = tid / 58;              // padded row 0..3
        const int wp = tid - pr * 58;         // padded col 0..57
        const int ih = h0 - 1 + pr;
        const int iw = wp - 1;
        const bool ok = ((unsigned)ih < 56u) && ((unsigned)iw < 56u);
        const float* xs = x + (size_t)n * CHW + ih * W_IN + iw;
        ushort_t* dst = patch + tid * 128;
        const int wkey = wp & 7;
        #pragma unroll
        for (int cg = 0; cg < 16; ++cg) {
            ushort8 v;
            #pragma unroll
            for (int j = 0; j < 8; ++j) {
                float f = 0.0f;
                if (ok) f = xs[(size_t)(cg * 8 + j) * HW];
                v[j] = f2bf(f);
            }
            *(ushort8*)(dst + (((cg ^ wkey)) << 3)) = v;
        }
    }
    __syncthreads();   // the ONLY barrier

    // per-lane B geometry (7 pixel fragments of 16)
    int ppix[7], wk[7], obo[7];
    #pragma unroll
    for (int u = 0; u < 7; ++u) {
        int pix = u * 16 + l15;               // 0..111
        int pr  = (pix >= 56) ? 1 : 0;
        int ww  = pix - pr * 56;
        ppix[u] = (pr * 58 + ww) * 128;       // ushort idx at (kh=0,kw=0)
        wk[u]   = ww;
        obo[u]  = (h0 + pr) * W_IN + ww;
    }

    // per-lane A offsets within a weight stage: o*64 + quad*8 (ushorts)
    int aoff[4];
    #pragma unroll
    for (int t = 0; t < 4; ++t)
        aoff[t] = ((om + t * 16 + l15) << 6) + (quad << 3);

    f32x4 acc[4][7];
    #pragma unroll
    for (int t = 0; t < 4; ++t)
        #pragma unroll
        for (int u = 0; u < 7; ++u)
            acc[t][u] = f32x4{0.f, 0.f, 0.f, 0.f};

    // ---- register-pipelined main loop: 36 iterations (18 stages x 2 ks) ----
    bf16x8 afb[2][4];   // weight frags, prefetch distance 2 (double-buffered)
    bf16x8 bvb[2][7];   // patch frags,  prefetch distance 1 (double-buffered)

#define LOAD_AF(it, buf) { \
    const ushort_t* wsp_ = wbf + ((it) >> 1) * 16384 + ((it) & 1) * 32; \
    _Pragma("unroll") \
    for (int t_ = 0; t_ < 4; ++t_) \
        (buf)[t_] = *(const bf16x8*)(wsp_ + aoff[t_]); }

#define LOAD_BV(it, buf) { \
    const int s_    = (it) >> 1; \
    const int ks_   = (it) & 1; \
    const int kh_   = (s_ >> 1) / 3; \
    const int kw_   = (s_ >> 1) % 3; \
    const int half_ = s_ & 1; \
    const int poff_ = (kh_ * 58 + kw_) * 128; \
    const int k16_  = half_ * 8 + ks_ * 4 + quad; \
    _Pragma("unroll") \
    for (int u_ = 0; u_ < 7; ++u_) { \
        const int slot_ = k16_ ^ ((wk[u_] + kw_) & 7); \
        (buf)[u_] = *(const bf16x8*)(patch + ppix[u_] + poff_ + (slot_ << 3)); } }

    LOAD_AF(0, afb[0]);
    LOAD_BV(0, bvb[0]);
    LOAD_AF(1, afb[1]);

    #pragma unroll
    for (int it = 0; it < 36; ++it) {
        if (it + 1 < 36) LOAD_BV(it + 1, bvb[(it + 1) & 1]);
        #pragma unroll
        for (int t = 0; t < 4; ++t)
            #pragma unroll
            for (int u = 0; u < 7; ++u)
                acc[t][u] = __builtin_amdgcn_mfma_f32_16x16x32_bf16(
                                afb[it & 1][t], bvb[it & 1][u], acc[t][u], 0, 0, 0);
        if (it + 2 < 36) LOAD_AF(it + 2, afb[it & 1]);   // reuse just-consumed buffer
    }
#undef LOAD_AF
#undef LOAD_BV

    // ---- epilogue ----
    f32x4 bv[4];
    #pragma unroll
    for (int t = 0; t < 4; ++t)
        bv[t] = *(const f32x4*)(bias + om + t * 16 + quad * 4);
    float* outn = out + (size_t)n * OHW;
    #pragma unroll
    for (int u = 0; u < 7; ++u) {
        float* op = outn + obo[u];
        #pragma unroll
        for (int t = 0; t < 4; ++t) {
            const int o0 = om + t * 16 + quad * 4;
            #pragma unroll
            for (int r = 0; r < 4; ++r)
                op[(size_t)(o0 + r) * HW] = acc[t][u][r] + bv[t][r];
        }
    }
}

// ============================ FALLBACK (known-correct) ============================

__global__ void wt_kernel(const float* __restrict__ w, ushort_t* __restrict__ wbf) {
    int idx = blockIdx.x * 256 + threadIdx.x;        // 9*256*128 = 294912
    if (idx >= 9 * 256 * 128) return;
    int pos = idx >> 15;
    int rem = idx & 32767;
    int o   = rem >> 7;
    int c   = rem & 127;
    wbf[idx] = f2bf(w[o * 1152 + c * 9 + pos]);
}

__global__ __launch_bounds__(512, 4)
void conv_kernel(const float* __restrict__ x, const ushort_t* __restrict__ wbf,
                 const float* __restrict__ bias, float* __restrict__ out) {
    __shared__ ushort_t As[256 * LDK];
    __shared__ ushort_t Bs[128 * LDK];

    const int tid  = threadIdx.x;
    const int lane = tid & 63;
    const int wave = tid >> 6;
    const int wm   = wave >> 1;
    const int wn   = wave & 1;
    const int l15  = lane & 15;
    const int quad = lane >> 4;

    const int pix_base = blockIdx.x * 128;
    const int px  = tid & 127;
    const int cg0 = tid >> 7;
    const int p   = pix_base + px;
    const int n_img = p / HW;
    const int hw    = p - n_img * HW;
    const int h     = hw / W_IN;
    const int w_    = hw - h * W_IN;
    const float* ximg = x + (long)n_img * CHW;

    f32x4 acc[4][4];
    #pragma unroll
    for (int t = 0; t < 4; ++t)
        #pragma unroll
        for (int u = 0; u < 4; ++u)
            acc[t][u] = f32x4{0.f, 0.f, 0.f, 0.f};

    for (int pos = 0; pos < 9; ++pos) {
        const int dh = pos / 3 - 1;
        const int dw = pos - (pos / 3) * 3 - 1;
        const int ih = h + dh;
        const int iw = w_ + dw;
        const bool valid = ((unsigned)ih < (unsigned)H_IN) && ((unsigned)iw < (unsigned)W_IN);
        const float* xsrc = ximg + ih * W_IN + iw;

        for (int half = 0; half < 2; ++half) {
            const int c0 = half * 64;
            {
                const ushort_t* wsrc = wbf + ((pos * 256) << 7) + c0;
                #pragma unroll
                for (int sj = 0; sj < 4; ++sj) {
                    const int o  = (tid >> 3) + sj * 64;
                    const int cg = tid & 7;
                    ushort8 v = *(const ushort8*)(wsrc + (o << 7) + cg * 8);
                    *(ushort8*)(&As[o * LDK + cg * 8]) = v;
                }
            }
            {
                #pragma unroll
                for (int sj = 0; sj < 2; ++sj) {
                    const int cg = cg0 + sj * 4;
                    const float* src = xsrc + (long)(c0 + cg * 8) * HW;
                    ushort8 v;
                    #pragma unroll
                    for (int j = 0; j < 8; ++j) {
                        float f = valid ? src[j * HW] : 0.0f;
                        v[j] = f2bf(f);
                    }
                    *(ushort8*)(&Bs[px * LDK + cg * 8]) = v;
                }
            }
            __syncthreads();

            #pragma unroll
            for (int ks = 0; ks < 2; ++ks) {
                bf16x8 af[4], bfv[4];
                #pragma unroll
                for (int t = 0; t < 4; ++t) {
                    const int row = wm * 64 + t * 16 + l15;
                    af[t] = *(const bf16x8*)(&As[row * LDK + ks * 32 + quad * 8]);
                }
                #pragma unroll
                for (int u = 0; u < 4; ++u) {
                    const int col = wn * 64 + u * 16 + l15;
                    bfv[u] = *(const bf16x8*)(&Bs[col * LDK + ks * 32 + quad * 8]);
                }
                #pragma unroll
                for (int t = 0; t < 4; ++t)
                    #pragma unroll
                    for (int u = 0; u < 4; ++u)
                        acc[t][u] = __builtin_amdgcn_mfma_f32_16x16x32_bf16(af[t], bfv[u], acc[t][u], 0, 0, 0);
            }
            __syncthreads();
        }
    }

    #pragma unroll
    for (int u = 0; u < 4; ++u) {
        const int col = wn * 64 + u * 16 + l15;
        const int pp  = pix_base + col;
        const int hw2 = pp - (pp / HW) * HW;
        const long obase = (long)(pp / HW) * OHW + hw2;
        #pragma unroll
        for (int t = 0; t < 4; ++t) {
            const int o_base = wm * 64 + t * 16 + quad * 4;
            #pragma unroll
            for (int r = 0; r < 4; ++r) {
                const int o = o_base + r;
                out[obase + (long)o * HW] = acc[t][u][r] + bias[o];
            }
        }
    }
}

extern "C" void kernel_launch(void* const* d_in, const int* in_sizes, int n_in,
                              void* d_out, int out_size, void* d_ws, size_t ws_size,
                              hipStream_t stream) {
    const float* x    = (const float*)d_in[0];
    const float* w    = (const float*)d_in[1];
    const float* bias = (const float*)d_in[2];
    float* out        = (float*)d_out;

    ushort_t* wbf = (ushort_t*)d_ws;                 // 589,824 B

    if (ws_size >= 589824u) {
        hipLaunchKernelGGL(wt3_kernel, dim3(1152), dim3(256), 0, stream, w, wbf);
        hipLaunchKernelGGL(conv7_kernel, dim3(896), dim3(256), 0, stream,
                           x, wbf, bias, out);
    } else {
        hipLaunchKernelGGL(wt_kernel, dim3(1152), dim3(256), 0, stream, w, wbf);
        hipLaunchKernelGGL(conv_kernel, dim3(100352 / 128), dim3(512), 0, stream,
                           x, wbf, bias, out);
    }
}

// Round 7
// 214.762 us; speedup vs baseline: 1.0806x; 1.0806x over previous
//
#include <hip/hip_runtime.h>

#define C_IN   128
#define H_IN   56
#define W_IN   56
#define HW     3136      // 56*56
#define CHW    401408    // 128*3136
#define O_OUT  256
#define OHW    802816    // 256*3136

#define LDK 72           // fallback padded layout

typedef __bf16 bf16x8 __attribute__((ext_vector_type(8)));
typedef float  f32x4  __attribute__((ext_vector_type(4)));
typedef unsigned short ushort_t;
typedef ushort_t ushort8 __attribute__((ext_vector_type(8)));

__device__ __forceinline__ ushort_t f2bf(float f) {
    union { float f; unsigned u; } v; v.f = f;
    unsigned r = (v.u + 0x7fffu + ((v.u >> 16) & 1u)) >> 16;
    return (ushort_t)r;
}

typedef const __attribute__((address_space(1))) unsigned int* gas_ptr;
typedef __attribute__((address_space(3))) unsigned int* las_ptr;
__device__ __forceinline__ void gl_lds16(const void* g, void* l) {
    // async global->LDS, 16B/lane; LDS dest MUST be a wave-uniform expression
    __builtin_amdgcn_global_load_lds((gas_ptr)g, (las_ptr)l, 16, 0, 0);
}

// ============================ FAST PATH ============================
// Weights -> k-major units: wbf[q][k8][o][e] bf16, q=0..35.
// q -> (pos = q>>2, c-chunk = q&3); c = (q&3)*32 + k8*8 + e.
// k-major makes conv10's A-frag ds_reads 2-way-bank-free with NO swizzle:
// byte = k8*4096 + o*16 -> 16 consecutive o -> 16 distinct bank-quads.
__global__ void wt4_kernel(const float* __restrict__ w, ushort_t* __restrict__ wbf) {
    int idx = blockIdx.x * 256 + threadIdx.x;        // 36*8192 = 294912
    if (idx >= 294912) return;
    int q  = idx >> 13;          // 0..35
    int r  = idx & 8191;
    int k8 = r >> 11;            // 0..3
    int o  = (r >> 3) & 255;
    int e  = r & 7;
    int c  = (q & 3) * 32 + k8 * 8 + e;
    int pos = q >> 2;
    wbf[idx] = f2bf(w[o * 1152 + c * 9 + pos]);
}

// conv10: T3+T4+T5 schedule (counted vmcnt across raw barriers + setprio),
// dynamic main loop + wave-uniform global_load_lds destinations.
//  - 512 thr / 8 waves (2/SIMD), tile 256o x 224px (4 output rows)
//  - patch: 6 padded rows x 58 x 128ch bf16, XOR-swizzled, staged ONCE (89088 B)
//  - weights: 36 units x 16 KB through a 3-slot LDS ring via global_load_lds;
//    per unit: issue q+2 -> ds_read frags -> setprio+28 MFMA -> vmcnt(2) -> s_barrier
//    (unit q+2's loads stay IN FLIGHT across the barrier; never drain in-loop)
__global__ __launch_bounds__(512, 2)
void conv10_kernel(const float* __restrict__ x, const ushort_t* __restrict__ wbf,
                   const float* __restrict__ bias, float* __restrict__ out) {
    __shared__ ushort_t patch[348 * 128];   // 89,088 B
    __shared__ ushort_t ring[3][8192];      // 49,152 B  (total 138,240 B)

    const int tid  = threadIdx.x;
    const int lane = tid & 63;
    const int wave = tid >> 6;      // 0..7
    const int wm   = wave >> 1;     // 0..3  o-slice (64 o)
    const int wn   = wave & 1;      // 0..1  px-half (112 px)
    const int l15  = lane & 15;
    const int quad = lane >> 4;
    const int om   = wm * 64;
    const int wbase = wave << 10;   // wave-uniform: 1024 B per wave per 8 KB call

    // block -> (n, h0); XCD-aware bijective swizzle (448 = 8 * 56)
    int b = blockIdx.x;
    b = (b & 7) * 56 + (b >> 3);
    const int n  = b / 14;
    const int h0 = (b - n * 14) * 4;

    // ---- one-time staging: x fp32 NCHW -> patch bf16 [row][slot^] ----
    if (tid < 348) {
        const int pr = tid / 58;              // padded row 0..5
        const int wp = tid - pr * 58;         // padded col 0..57
        const int ih = h0 - 1 + pr;
        const int iw = wp - 1;
        const bool ok = ((unsigned)ih < 56u) && ((unsigned)iw < 56u);
        const float* xs = x + (size_t)n * CHW + ih * W_IN + iw;
        ushort_t* dst = patch + tid * 128;
        const int wkey = wp & 7;
        #pragma unroll
        for (int cg = 0; cg < 16; ++cg) {
            ushort8 v;
            #pragma unroll
            for (int j = 0; j < 8; ++j) {
                float f = 0.0f;
                if (ok) f = xs[(size_t)(cg * 8 + j) * HW];
                v[j] = f2bf(f);
            }
            *(ushort8*)(dst + ((cg ^ wkey) << 3)) = v;
        }
    }
    // prologue: weight units 0,1 into ring slots 0,1 (wave-uniform LDS dests)
    {
        const char* wg = (const char*)wbf;
        #pragma unroll
        for (int qq = 0; qq < 2; ++qq)
            #pragma unroll
            for (int j = 0; j < 2; ++j)
                gl_lds16(wg + qq * 16384 + j * 8192 + wbase + (lane << 4),
                         (char*)ring[qq] + j * 8192 + wbase);
    }
    asm volatile("s_waitcnt vmcnt(0)" ::: "memory");
    __syncthreads();

    // per-lane B geometry (7 pixel fragments of 16, spanning 4 output rows)
    int ppix[7], wk[7], obo[7];
    #pragma unroll
    for (int u = 0; u < 7; ++u) {
        int pix = wn * 112 + u * 16 + l15;    // 0..223
        int pr  = pix / 56;                   // 0..3
        int ww  = pix - pr * 56;              // 0..55
        ppix[u] = (pr * 58 + ww) * 128;       // patch ushort offset at (kh=0,kw=0)
        wk[u]   = ww;
        obo[u]  = (h0 + pr) * W_IN + ww;
    }

    f32x4 acc[4][7];
    #pragma unroll
    for (int t = 0; t < 4; ++t)
        #pragma unroll
        for (int u = 0; u < 7; ++u)
            acc[t][u] = f32x4{0.f, 0.f, 0.f, 0.f};

    // ---- main loop: 36 units, counted-vmcnt pipeline, rotating 3-slot ring ----
    ushort_t* r0 = ring[0];   // unit q      (read this iter)
    ushort_t* r1 = ring[1];   // unit q+1    (landed by this iter's vmcnt)
    ushort_t* r2 = ring[2];   // unit q+2    (written this iter)

    for (int q = 0; q < 36; ++q) {
        // issue unit q+2 into the slot freed after unit q-1
        if (q < 34) {
            const char* src = (const char*)wbf + (size_t)(q + 2) * 16384;
            char* d = (char*)r2;
            gl_lds16(src + wbase + (lane << 4),        d + wbase);
            gl_lds16(src + 8192 + wbase + (lane << 4), d + 8192 + wbase);
        }

        // fragment reads (compiler inserts fine-grained lgkmcnt before MFMAs)
        const int pos = q >> 2;
        const int kh  = pos / 3;
        const int kw  = pos - kh * 3;
        const int poff = (kh * 58 + kw) * 128;
        const int cg   = (q & 3) * 4 + quad;

        bf16x8 af[4], bfv[7];
        #pragma unroll
        for (int t = 0; t < 4; ++t)
            af[t] = *(const bf16x8*)(r0 + quad * 2048 + (om + t * 16 + l15) * 8);
        #pragma unroll
        for (int u = 0; u < 7; ++u) {
            const int slot = cg ^ ((wk[u] + kw) & 7);
            bfv[u] = *(const bf16x8*)(patch + ppix[u] + poff + (slot << 3));
        }

        __builtin_amdgcn_s_setprio(1);
        #pragma unroll
        for (int t = 0; t < 4; ++t)
            #pragma unroll
            for (int u = 0; u < 7; ++u)
                acc[t][u] = __builtin_amdgcn_mfma_f32_16x16x32_bf16(
                                af[t], bfv[u], acc[t][u], 0, 0, 0);
        __builtin_amdgcn_s_setprio(0);

        // counted wait: unit q+1 landed; unit q+2 stays in flight across barrier
        __builtin_amdgcn_sched_barrier(0);
        if (q < 34) asm volatile("s_waitcnt vmcnt(2)" ::: "memory");
        else        asm volatile("s_waitcnt vmcnt(0)" ::: "memory");
        __builtin_amdgcn_s_barrier();
        __builtin_amdgcn_sched_barrier(0);

        // rotate ring pointers
        ushort_t* tmp = r0; r0 = r1; r1 = r2; r2 = tmp;
    }

    // ---- epilogue ----
    f32x4 bv[4];
    #pragma unroll
    for (int t = 0; t < 4; ++t)
        bv[t] = *(const f32x4*)(bias + om + t * 16 + quad * 4);
    float* outn = out + (size_t)n * OHW;
    #pragma unroll
    for (int u = 0; u < 7; ++u) {
        float* op = outn + obo[u];
        #pragma unroll
        for (int t = 0; t < 4; ++t) {
            const int o0 = om + t * 16 + quad * 4;
            #pragma unroll
            for (int r = 0; r < 4; ++r)
                op[(size_t)(o0 + r) * HW] = acc[t][u][r] + bv[t][r];
        }
    }
}

// ============================ FALLBACK (known-correct) ============================

__global__ void wt_kernel(const float* __restrict__ w, ushort_t* __restrict__ wbf) {
    int idx = blockIdx.x * 256 + threadIdx.x;        // 9*256*128 = 294912
    if (idx >= 9 * 256 * 128) return;
    int pos = idx >> 15;
    int rem = idx & 32767;
    int o   = rem >> 7;
    int c   = rem & 127;
    wbf[idx] = f2bf(w[o * 1152 + c * 9 + pos]);
}

__global__ __launch_bounds__(512, 4)
void conv_kernel(const float* __restrict__ x, const ushort_t* __restrict__ wbf,
                 const float* __restrict__ bias, float* __restrict__ out) {
    __shared__ ushort_t As[256 * LDK];
    __shared__ ushort_t Bs[128 * LDK];

    const int tid  = threadIdx.x;
    const int lane = tid & 63;
    const int wave = tid >> 6;
    const int wm   = wave >> 1;
    const int wn   = wave & 1;
    const int l15  = lane & 15;
    const int quad = lane >> 4;

    const int pix_base = blockIdx.x * 128;
    const int px  = tid & 127;
    const int cg0 = tid >> 7;
    const int p   = pix_base + px;
    const int n_img = p / HW;
    const int hw    = p - n_img * HW;
    const int h     = hw / W_IN;
    const int w_    = hw - h * W_IN;
    const float* ximg = x + (long)n_img * CHW;

    f32x4 acc[4][4];
    #pragma unroll
    for (int t = 0; t < 4; ++t)
        #pragma unroll
        for (int u = 0; u < 4; ++u)
            acc[t][u] = f32x4{0.f, 0.f, 0.f, 0.f};

    for (int pos = 0; pos < 9; ++pos) {
        const int dh = pos / 3 - 1;
        const int dw = pos - (pos / 3) * 3 - 1;
        const int ih = h + dh;
        const int iw = w_ + dw;
        const bool valid = ((unsigned)ih < (unsigned)H_IN) && ((unsigned)iw < (unsigned)W_IN);
        const float* xsrc = ximg + ih * W_IN + iw;

        for (int half = 0; half < 2; ++half) {
            const int c0 = half * 64;
            {
                const ushort_t* wsrc = wbf + ((pos * 256) << 7) + c0;
                #pragma unroll
                for (int sj = 0; sj < 4; ++sj) {
                    const int o  = (tid >> 3) + sj * 64;
                    const int cg = tid & 7;
                    ushort8 v = *(const ushort8*)(wsrc + (o << 7) + cg * 8);
                    *(ushort8*)(&As[o * LDK + cg * 8]) = v;
                }
            }
            {
                #pragma unroll
                for (int sj = 0; sj < 2; ++sj) {
                    const int cg = cg0 + sj * 4;
                    const float* src = xsrc + (long)(c0 + cg * 8) * HW;
                    ushort8 v;
                    #pragma unroll
                    for (int j = 0; j < 8; ++j) {
                        float f = valid ? src[j * HW] : 0.0f;
                        v[j] = f2bf(f);
                    }
                    *(ushort8*)(&Bs[px * LDK + cg * 8]) = v;
                }
            }
            __syncthreads();

            #pragma unroll
            for (int ks = 0; ks < 2; ++ks) {
                bf16x8 af[4], bfv[4];
                #pragma unroll
                for (int t = 0; t < 4; ++t) {
                    const int row = wm * 64 + t * 16 + l15;
                    af[t] = *(const bf16x8*)(&As[row * LDK + ks * 32 + quad * 8]);
                }
                #pragma unroll
                for (int u = 0; u < 4; ++u) {
                    const int col = wn * 64 + u * 16 + l15;
                    bfv[u] = *(const bf16x8*)(&Bs[col * LDK + ks * 32 + quad * 8]);
                }
                #pragma unroll
                for (int t = 0; t < 4; ++t)
                    #pragma unroll
                    for (int u = 0; u < 4; ++u)
                        acc[t][u] = __builtin_amdgcn_mfma_f32_16x16x32_bf16(af[t], bfv[u], acc[t][u], 0, 0, 0);
            }
            __syncthreads();
        }
    }

    #pragma unroll
    for (int u = 0; u < 4; ++u) {
        const int col = wn * 64 + u * 16 + l15;
        const int pp  = pix_base + col;
        const int hw2 = pp - (pp / HW) * HW;
        const long obase = (long)(pp / HW) * OHW + hw2;
        #pragma unroll
        for (int t = 0; t < 4; ++t) {
            const int o_base = wm * 64 + t * 16 + quad * 4;
            #pragma unroll
            for (int r = 0; r < 4; ++r) {
                const int o = o_base + r;
                out[obase + (long)o * HW] = acc[t][u][r] + bias[o];
            }
        }
    }
}

extern "C" void kernel_launch(void* const* d_in, const int* in_sizes, int n_in,
                              void* d_out, int out_size, void* d_ws, size_t ws_size,
                              hipStream_t stream) {
    const float* x    = (const float*)d_in[0];
    const float* w    = (const float*)d_in[1];
    const float* bias = (const float*)d_in[2];
    float* out        = (float*)d_out;

    ushort_t* wbf = (ushort_t*)d_ws;                 // 589,824 B

    if (ws_size >= 589824u) {
        hipLaunchKernelGGL(wt4_kernel, dim3(1152), dim3(256), 0, stream, w, wbf);
        hipLaunchKernelGGL(conv10_kernel, dim3(448), dim3(512), 0, stream,
                           x, wbf, bias, out);
    } else {
        hipLaunchKernelGGL(wt_kernel, dim3(1152), dim3(256), 0, stream, w, wbf);
        hipLaunchKernelGGL(conv_kernel, dim3(100352 / 128), dim3(512), 0, stream,
                           x, wbf, bias, out);
    }
}

// Round 9
// 209.631 us; speedup vs baseline: 1.1070x; 1.0245x over previous
//
#include <hip/hip_runtime.h>

#define C_IN   128
#define H_IN   56
#define W_IN   56
#define HW     3136      // 56*56
#define CHW    401408    // 128*3136
#define O_OUT  256
#define OHW    802816    // 256*3136

#define LDK 72           // fallback padded layout
#define XTP 132          // xt2 transpose LDS row stride (ushorts)

typedef __bf16 bf16x8 __attribute__((ext_vector_type(8)));
typedef float  f32x4  __attribute__((ext_vector_type(4)));
typedef unsigned short ushort_t;
typedef ushort_t ushort8 __attribute__((ext_vector_type(8)));

__device__ __forceinline__ ushort_t f2bf(float f) {
    union { float f; unsigned u; } v; v.f = f;
    unsigned r = (v.u + 0x7fffu + ((v.u >> 16) & 1u)) >> 16;
    return (ushort_t)r;
}

typedef const __attribute__((address_space(1))) unsigned int* gas_ptr;
typedef __attribute__((address_space(3))) unsigned int* las_ptr;
__device__ __forceinline__ void gl_lds16(const void* g, void* l) {
    // async global->LDS, 16B/lane; LDS dest must be wave-uniform
    __builtin_amdgcn_global_load_lds((gas_ptr)g, (las_ptr)l, 16, 0, 0);
}

// ============================ FAST PATH ============================

// Weights: w[o][c][kh][kw] fp32 -> wbf[s][o][slot][8] bf16,
// s = (kh*3+kw)*2 + (c>>6); slot = ((c>>3)&7) ^ (o&7)   [round-1 wt2, proven]
__global__ void wt2_kernel(const float* __restrict__ w, ushort_t* __restrict__ wbf) {
    int idx = blockIdx.x * 256 + threadIdx.x;        // 9*256*128 = 294912
    if (idx >= 9 * 256 * 128) return;
    int pos = idx >> 15;
    int rem = idx & 32767;
    int o   = rem >> 7;
    int c   = rem & 127;
    int s    = pos * 2 + (c >> 6);
    int slot = ((c >> 3) & 7) ^ (o & 7);
    wbf[((s * 256 + o) << 6) + (slot << 3) + (c & 7)] = f2bf(w[o * 1152 + c * 9 + pos]);
}

// x fp32 NCHW -> padded swizzled bf16 NHWC: xbp[n][h'][w'][slot][8],
// h',w' in [0,58), borders zero, slot = gg ^ (w'&7).    [round-1 xt2, proven]
__global__ __launch_bounds__(256)
void xt2_kernel(const float* __restrict__ x, ushort_t* __restrict__ xbp) {
    const int b  = blockIdx.x;            // 0..1855  (32*58)
    const int n  = b / 58;
    const int hp = b - n * 58;
    ushort_t* orow = xbp + (size_t)(n * 58 + hp) * 7424;
    const int t = threadIdx.x;
    ushort8 z = ushort8{0,0,0,0,0,0,0,0};

    if (hp == 0 || hp == 57) {
        #pragma unroll
        for (int i = 0; i < 4; ++i) {
            int u = i * 256 + t;
            if (u < 928) *(ushort8*)(orow + u * 8) = z;
        }
        return;
    }

    __shared__ ushort_t T[56 * XTP];      // [w][c], 14784 B
    const int h = hp - 1;
    const float* src = x + (size_t)n * CHW + h * W_IN;
    #pragma unroll
    for (int i = 0; i < 7; ++i) {
        int g  = i * 256 + t;             // 0..1791 = 128 ch * 14 float4
        int c  = g / 14;
        int f4 = g - c * 14;
        f32x4 v = *(const f32x4*)(src + (size_t)c * HW + f4 * 4);
        #pragma unroll
        for (int j = 0; j < 4; ++j)
            T[(f4 * 4 + j) * XTP + c] = f2bf(v[j]);
    }
    __syncthreads();
    #pragma unroll
    for (int i = 0; i < 4; ++i) {
        int u = i * 256 + t;              // 0..927 = 58 w' * 16 groups
        if (u < 928) {
            int wp = u >> 4, gg = u & 15;
            ushort8 v = (wp == 0 || wp == 57) ? z
                        : *(const ushort8*)(&T[(wp - 1) * XTP + gg * 8]);
            *(ushort8*)(orow + wp * 128 + ((gg ^ (wp & 7)) << 3)) = v;
        }
    }
}

// conv12: m97-regime implicit GEMM (conv11 + fixed B-deswizzle key).
//  - tile 128o x 128px, 256 thr / 4 waves, LDS 32 KB -> 3 blocks/CU (12 waves)
//  - both operands staged per stage by LINEAR global_load_lds (16B) from
//    pre-swizzled global layouts (wt2 / xt2); frag reads XOR-deswizzle.
//  - plain 2-barrier loop x 18 stages; cross-block TLP hides the drains.
__global__ __launch_bounds__(256, 3)
void conv12_kernel(const ushort_t* __restrict__ xbp, const ushort_t* __restrict__ wbf,
                   const float* __restrict__ bias, float* __restrict__ out) {
    __shared__ ushort_t As[128 * 64];   // 16 KB  [o_local][slot^(o&7)][8]
    __shared__ ushort_t Bs[128 * 64];   // 16 KB  [px][j8 = g8^(w'&7)][8]

    const int tid  = threadIdx.x;
    const int lane = tid & 63;
    const int wave = tid >> 6;      // 0..3
    const int wm   = wave >> 1;     // o half (64)
    const int wn   = wave & 1;      // px half (64)
    const int l15  = lane & 15;
    const int quad = lane >> 4;
    const int om   = wm * 64;

    // tile id, XCD-aware bijective swizzle (1568 = 8*196)
    int tau = blockIdx.x;
    tau = (tau & 7) * 196 + (tau >> 3);
    const int pix_base = (tau >> 1) * 128;
    const int ob       = (tau & 1) << 7;

    // ---- per-thread B staging bases (4 gl_lds calls/stage/wave) ----
    // call c: idx = (wave*4+c)*64 + lane; px = idx>>3; j8 = idx&7
    long Bc[4];
    {
        #pragma unroll
        for (int c = 0; c < 4; ++c) {
            int idx = (wave * 4 + c) * 64 + lane;
            int px  = idx >> 3;
            int j8  = idx & 7;
            int p   = pix_base + px;
            int n_  = p / HW;
            int hw  = p - n_ * HW;
            int h   = hw / W_IN;
            int w_  = hw - h * W_IN;
            // byte address at (dh=0, dw=0, half=0): ((n*58 + h+1)*58 + (w+1))*256 + j8*16
            Bc[c] = (long)(n_ * 58 + h + 1) * 14848 + (long)(w_ + 1) * 256 + j8 * 16;
        }
    }

    // ---- per-lane A frag LDS byte offsets (ks=0), and B pixel info ----
    int aoff[4];
    #pragma unroll
    for (int t = 0; t < 4; ++t) {
        int ol = om + t * 16 + l15;
        aoff[t] = ol * 128 + ((quad ^ (ol & 7)) << 4);
    }
    int pxb[4], pr7[4], obo[4];
    #pragma unroll
    for (int u = 0; u < 4; ++u) {
        int pxr = wn * 64 + u * 16 + l15;
        int p   = pix_base + pxr;
        pxb[u]  = pxr * 128;
        pr7[u]  = (p + 1) & 7;          // (w+1)&7, since HW,56 ≡ 0 mod 8
        obo[u]  = p;                    // global pixel for epilogue
    }

    f32x4 acc[4][4];
    #pragma unroll
    for (int t = 0; t < 4; ++t)
        #pragma unroll
        for (int u = 0; u < 4; ++u)
            acc[t][u] = f32x4{0.f, 0.f, 0.f, 0.f};

    const char* xg = (const char*)xbp;
    const char* wg = (const char*)wbf;
    char* AsB = (char*)As;
    char* BsB = (char*)Bs;

    for (int q = 0; q < 18; ++q) {
        const int pos  = q >> 1;
        const int half = q & 1;
        const int dh   = pos / 3 - 1;
        const int dw   = pos - (pos / 3) * 3 - 1;
        const long soff = (long)dh * 14848 + (long)dw * 256 + half * 128;

        // ---- stage A (16 KB) and B (16 KB), linear gl_lds ----
        {
            const char* as = wg + (size_t)q * 32768 + (size_t)ob * 128;
            #pragma unroll
            for (int j = 0; j < 4; ++j) {
                const int blk = (wave * 4 + j) * 1024;
                gl_lds16(as + blk + (lane << 4), AsB + blk);
                gl_lds16(xg + Bc[j] + soff,      BsB + blk);
            }
        }
        __syncthreads();   // drains vmcnt (gl_lds landed)

        // ---- compute: 2 ks x 16 MFMA ----
        // source pixel padded col = w_ + dw + 1  ->  key = (pr7 + dw) & 7
        // (round-8 fix: was (pr7 + dw + 1) & 7 -- off by one, absmax 285)
        int boff[4];
        #pragma unroll
        for (int u = 0; u < 4; ++u) {
            const int key = (pr7[u] + dw + 8) & 7;
            boff[u] = pxb[u] + ((quad ^ key) << 4);
        }
        #pragma unroll
        for (int ks = 0; ks < 2; ++ks) {
            const int kx = ks << 6;   // XOR 64 bytes flips slot bit 2
            bf16x8 af[4], bf[4];
            #pragma unroll
            for (int t = 0; t < 4; ++t)
                af[t] = *(const bf16x8*)(AsB + (aoff[t] ^ kx));
            #pragma unroll
            for (int u = 0; u < 4; ++u)
                bf[u] = *(const bf16x8*)(BsB + (boff[u] ^ kx));
            #pragma unroll
            for (int t = 0; t < 4; ++t)
                #pragma unroll
                for (int u = 0; u < 4; ++u)
                    acc[t][u] = __builtin_amdgcn_mfma_f32_16x16x32_bf16(
                                    af[t], bf[u], acc[t][u], 0, 0, 0);
        }
        __syncthreads();   // protect LDS before next stage overwrites
    }

    // ---- epilogue (conv2-proven mapping, + ob) ----
    #pragma unroll
    for (int u = 0; u < 4; ++u) {
        const int pp  = obo[u];
        const int nn  = pp / HW;
        const int hw2 = pp - nn * HW;
        const long obase = (long)nn * OHW + hw2;
        #pragma unroll
        for (int t = 0; t < 4; ++t) {
            const int o_base = ob + wm * 64 + t * 16 + quad * 4;
            #pragma unroll
            for (int r = 0; r < 4; ++r) {
                const int o = o_base + r;
                out[obase + (long)o * HW] = acc[t][u][r] + bias[o];
            }
        }
    }
}

// ============================ FALLBACK (known-correct) ============================

__global__ void wt_kernel(const float* __restrict__ w, ushort_t* __restrict__ wbf) {
    int idx = blockIdx.x * 256 + threadIdx.x;        // 9*256*128 = 294912
    if (idx >= 9 * 256 * 128) return;
    int pos = idx >> 15;
    int rem = idx & 32767;
    int o   = rem >> 7;
    int c   = rem & 127;
    wbf[idx] = f2bf(w[o * 1152 + c * 9 + pos]);
}

__global__ __launch_bounds__(512, 4)
void conv_kernel(const float* __restrict__ x, const ushort_t* __restrict__ wbf,
                 const float* __restrict__ bias, float* __restrict__ out) {
    __shared__ ushort_t As[256 * LDK];
    __shared__ ushort_t Bs[128 * LDK];

    const int tid  = threadIdx.x;
    const int lane = tid & 63;
    const int wave = tid >> 6;
    const int wm   = wave >> 1;
    const int wn   = wave & 1;
    const int l15  = lane & 15;
    const int quad = lane >> 4;

    const int pix_base = blockIdx.x * 128;
    const int px  = tid & 127;
    const int cg0 = tid >> 7;
    const int p   = pix_base + px;
    const int n_img = p / HW;
    const int hw    = p - n_img * HW;
    const int h     = hw / W_IN;
    const int w_    = hw - h * W_IN;
    const float* ximg = x + (long)n_img * CHW;

    f32x4 acc[4][4];
    #pragma unroll
    for (int t = 0; t < 4; ++t)
        #pragma unroll
        for (int u = 0; u < 4; ++u)
            acc[t][u] = f32x4{0.f, 0.f, 0.f, 0.f};

    for (int pos = 0; pos < 9; ++pos) {
        const int dh = pos / 3 - 1;
        const int dw = pos - (pos / 3) * 3 - 1;
        const int ih = h + dh;
        const int iw = w_ + dw;
        const bool valid = ((unsigned)ih < (unsigned)H_IN) && ((unsigned)iw < (unsigned)W_IN);
        const float* xsrc = ximg + ih * W_IN + iw;

        for (int half = 0; half < 2; ++half) {
            const int c0 = half * 64;
            {
                const ushort_t* wsrc = wbf + ((pos * 256) << 7) + c0;
                #pragma unroll
                for (int sj = 0; sj < 4; ++sj) {
                    const int o  = (tid >> 3) + sj * 64;
                    const int cg = tid & 7;
                    ushort8 v = *(const ushort8*)(wsrc + (o << 7) + cg * 8);
                    *(ushort8*)(&As[o * LDK + cg * 8]) = v;
                }
            }
            {
                #pragma unroll
                for (int sj = 0; sj < 2; ++sj) {
                    const int cg = cg0 + sj * 4;
                    const float* src = xsrc + (long)(c0 + cg * 8) * HW;
                    ushort8 v;
                    #pragma unroll
                    for (int j = 0; j < 8; ++j) {
                        float f = valid ? src[j * HW] : 0.0f;
                        v[j] = f2bf(f);
                    }
                    *(ushort8*)(&Bs[px * LDK + cg * 8]) = v;
                }
            }
            __syncthreads();

            #pragma unroll
            for (int ks = 0; ks < 2; ++ks) {
                bf16x8 af[4], bfv[4];
                #pragma unroll
                for (int t = 0; t < 4; ++t) {
                    const int row = wm * 64 + t * 16 + l15;
                    af[t] = *(const bf16x8*)(&As[row * LDK + ks * 32 + quad * 8]);
                }
                #pragma unroll
                for (int u = 0; u < 4; ++u) {
                    const int col = wn * 64 + u * 16 + l15;
                    bfv[u] = *(const bf16x8*)(&Bs[col * LDK + ks * 32 + quad * 8]);
                }
                #pragma unroll
                for (int t = 0; t < 4; ++t)
                    #pragma unroll
                    for (int u = 0; u < 4; ++u)
                        acc[t][u] = __builtin_amdgcn_mfma_f32_16x16x32_bf16(af[t], bfv[u], acc[t][u], 0, 0, 0);
            }
            __syncthreads();
        }
    }

    #pragma unroll
    for (int u = 0; u < 4; ++u) {
        const int col = wn * 64 + u * 16 + l15;
        const int pp  = pix_base + col;
        const int hw2 = pp - (pp / HW) * HW;
        const long obase = (long)(pp / HW) * OHW + hw2;
        #pragma unroll
        for (int t = 0; t < 4; ++t) {
            const int o_base = wm * 64 + t * 16 + quad * 4;
            #pragma unroll
            for (int r = 0; r < 4; ++r) {
                const int o = o_base + r;
                out[obase + (long)o * HW] = acc[t][u][r] + bias[o];
            }
        }
    }
}

extern "C" void kernel_launch(void* const* d_in, const int* in_sizes, int n_in,
                              void* d_out, int out_size, void* d_ws, size_t ws_size,
                              hipStream_t stream) {
    const float* x    = (const float*)d_in[0];
    const float* w    = (const float*)d_in[1];
    const float* bias = (const float*)d_in[2];
    float* out        = (float*)d_out;

    // fast path: wbf (589,824 B) + xbp (padded 58x58 NHWC, 27,557,888 B)
    const size_t NEED_NEW = 589824u + 27557888u;    // 28,147,712

    if (ws_size >= NEED_NEW) {
        ushort_t* wbf = (ushort_t*)d_ws;
        ushort_t* xbp = (ushort_t*)((char*)d_ws + 589824);
        hipLaunchKernelGGL(wt2_kernel, dim3(1152), dim3(256), 0, stream, w, wbf);
        hipLaunchKernelGGL(xt2_kernel, dim3(1856), dim3(256), 0, stream, x, xbp);
        hipLaunchKernelGGL(conv12_kernel, dim3(1568), dim3(256), 0, stream,
                           xbp, wbf, bias, out);
    } else {
        ushort_t* wbf = (ushort_t*)d_ws;
        hipLaunchKernelGGL(wt_kernel, dim3(1152), dim3(256), 0, stream, w, wbf);
        hipLaunchKernelGGL(conv_kernel, dim3(100352 / 128), dim3(512), 0, stream,
                           x, wbf, bias, out);
    }
}